// Round 5
// baseline (276.893 us; speedup 1.0000x reference)
//
#include <hip/hip_runtime.h>

#define D 128
#define MARGIN 1.0f
#define ALFA 0.1f
#define KC 64
#define GB 512        // gram blocks

// ws layout (floats):
// [0] tsum | [256..16640) gram | [16640..16768) colsum | [16896..) partials | bf16 table
#define WS_TSUM   0
#define WS_GRAM   256
#define WS_COLSUM (WS_GRAM + D * D)
#define WS_ZERO   (WS_COLSUM + D)
#define WS_PART   16896
#define PART_STRIDE (D * D + D)                   // 16512 floats per gram-block partial
#define WS_TAB_F  (WS_PART + GB * PART_STRIDE)    // float index of bf16 table start

typedef __attribute__((ext_vector_type(8)))  short bf16x8;
typedef __attribute__((ext_vector_type(8)))  unsigned short u16x8;
typedef __attribute__((ext_vector_type(16))) float f32x16;

__device__ __forceinline__ unsigned short f2bf(float f) {
    unsigned u = __float_as_uint(f);
    u += 0x7FFFu + ((u >> 16) & 1u);   // RNE
    return (unsigned short)(u >> 16);
}
__device__ __forceinline__ float bf2f(unsigned short u) {
    return __uint_as_float((unsigned)u << 16);
}

// ---------------------------------------------------------------------------
// Kernel A: Gram via bf16 MFMA (32x32x16) + bf16 table emission.
// GB blocks x 512 thr. Block owns N/GB rows; stages KC=64 rows transposed
// bf16 into LDS (double-buffered, XOR slot swizzle); the same bf16 values
// are streamed to the global bf16 table for kernel B's gathers.
// Gram is symmetric (G = X^T X) -> C/D transpose harmless.
// ---------------------------------------------------------------------------
__global__ __launch_bounds__(512, 4) void gram_mfma_write(const float* __restrict__ emb,
                                                          int rowsPerBlock,
                                                          float* __restrict__ ws,
                                                          unsigned short* __restrict__ tab) {
    __shared__ __align__(16) char lds[2][128 * 128];   // 32 KiB
    __shared__ float csred[D];

    const int tid = threadIdx.x;
    const int l   = tid & 63;
    const int w   = tid >> 6;
    const int r0  = blockIdx.x * rowsPerBlock;

    const int rT = w & 3;              // row tile 0..3
    const int c0 = (w >> 2) * 2;       // col tiles c0, c0+1

    f32x16 acc0 = {};
    f32x16 acc1 = {};
    float cs[4] = {0.f, 0.f, 0.f, 0.f};
    const int d0 = (tid & 31) * 4;     // dim group this thread stages

    auto stage = [&](int cc, int b) {
#pragma unroll
        for (int j = 0; j < 2; ++j) {
            const int k = j * 32 + (tid >> 5) * 2;   // even row in chunk
            const int rowg = r0 + cc * KC + k;       // global row of 'a'
            const float* base = emb + (size_t)rowg * D + d0;
            float4 a  = *(const float4*)base;
            float4 bv = *(const float4*)(base + D);
            ushort4 ua, ub;
            unsigned short* pa = (unsigned short*)&ua;
            unsigned short* pb = (unsigned short*)&ub;
#pragma unroll
            for (int i = 0; i < 4; ++i) {
                float av = ((const float*)&a)[i];
                float bb = ((const float*)&bv)[i];
                cs[i] += av + bb;
                unsigned short ha = f2bf(av), hb = f2bf(bb);
                pa[i] = ha; pb[i] = hb;
                unsigned slotp = (unsigned)(k >> 3) ^ (unsigned)((tid & 31) & 7); // == (d>>2)&7
                unsigned off = (unsigned)(d0 + i) * 128u + slotp * 16u + (unsigned)((k & 7) << 1);
                *(unsigned*)(&lds[b][off]) = (unsigned)ha | ((unsigned)hb << 16);
            }
            // bf16 table emission: 8B/lane, 256B contiguous per half-wave row
            *(ushort4*)&tab[(size_t)rowg * D + d0]       = ua;
            *(ushort4*)&tab[(size_t)(rowg + 1) * D + d0] = ub;
        }
    };

    auto frag = [&](int t, int kb, int b) -> bf16x8 {
        const int d = t * 32 + (l & 31);
        const int k = kb + (l >> 5) * 8;
        unsigned slotp = (unsigned)(k >> 3) ^ ((unsigned)(d >> 2) & 7u);
        return *(const bf16x8*)(&lds[b][(unsigned)d * 128u + slotp * 16u]);
    };

    const int nChunks = rowsPerBlock / KC;
    stage(0, 0);
    for (int cc = 0; cc < nChunks; ++cc) {
        const int b = cc & 1;
        __syncthreads();                       // buf b staged; buf b^1 free
        if (cc + 1 < nChunks) stage(cc + 1, b ^ 1);
#pragma unroll
        for (int kb = 0; kb < KC; kb += 16) {
            bf16x8 fr = frag(rT,     kb, b);
            bf16x8 f0 = frag(c0,     kb, b);
            bf16x8 f1 = frag(c0 + 1, kb, b);
            acc0 = __builtin_amdgcn_mfma_f32_32x32x16_bf16(fr, f0, acc0, 0, 0, 0);
            acc1 = __builtin_amdgcn_mfma_f32_32x32x16_bf16(fr, f1, acc1, 0, 0, 0);
        }
    }
    __syncthreads();

    if (tid < D) csred[tid] = 0.f;
    __syncthreads();
#pragma unroll
    for (int i = 0; i < 4; ++i) atomicAdd(&csred[d0 + i], cs[i]);
    __syncthreads();

    float* gram   = ws + WS_PART + (size_t)blockIdx.x * PART_STRIDE;
    float* colsum = gram + D * D;

    if (tid < D) colsum[tid] = csred[tid];

    // C/D layout (verified m74/m101): col = l&31, row = (reg&3)+8*(reg>>2)+4*(l>>5)
    const int row_hi = (l >> 5) * 4;
    const int col    = l & 31;
#pragma unroll
    for (int reg = 0; reg < 16; ++reg) {
        const int row32 = (reg & 3) + 8 * (reg >> 2) + row_hi;
        const int gr    = (rT * 32 + row32) * D;
        gram[gr + c0 * 32 + col]       = acc0[reg];
        gram[gr + (c0 + 1) * 32 + col] = acc1[reg];
    }
}

// ---------------------------------------------------------------------------
// Kernel B: triplet loss from the bf16 table. 16-lane group per triplet,
// ushort8 (16B) per lane covers 8 dims; 4 triplets in flight per group.
// ---------------------------------------------------------------------------
__global__ __launch_bounds__(256) void triplet_bf16(const unsigned short* __restrict__ tab,
                                                    const int* __restrict__ trip,
                                                    int T,
                                                    float* __restrict__ ws) {
    const int tid = threadIdx.x;
    const int li  = tid & 15;
    const int grp = (blockIdx.x * 256 + tid) >> 4;
    const int NG  = (gridDim.x * 256) >> 4;

    float wsum = 0.f;

    for (int t0 = grp; t0 < T; t0 += 4 * NG) {
        u16x8 P[4], Q[4], R[4];
#pragma unroll
        for (int u = 0; u < 4; ++u) {
            const int t = t0 + u * NG;
            if (t < T) {
                const int i0 = trip[3 * t], i1 = trip[3 * t + 1], i2 = trip[3 * t + 2];
                P[u] = *(const u16x8*)&tab[(size_t)i0 * D + li * 8];
                Q[u] = *(const u16x8*)&tab[(size_t)i1 * D + li * 8];
                R[u] = *(const u16x8*)&tab[(size_t)i2 * D + li * 8];
            }
        }
#pragma unroll
        for (int u = 0; u < 4; ++u) {
            const int t = t0 + u * NG;
            if (t < T) {
                float s = 0.f;
#pragma unroll
                for (int e = 0; e < 8; ++e) {
                    float p = bf2f(P[u][e]);
                    float dp = p - bf2f(Q[u][e]);
                    float dn = p - bf2f(R[u][e]);
                    s += dp * dp - dn * dn;
                }
#pragma unroll
                for (int off = 8; off; off >>= 1) s += __shfl_xor(s, off, 64);
                if (li == 0) wsum += fmaxf(s + MARGIN, 0.f);
            }
        }
    }

    __shared__ float red[16];
    if (li == 0) red[tid >> 4] = wsum;
    __syncthreads();
    if (tid == 0) {
        float b = 0.f;
#pragma unroll
        for (int i = 0; i < 16; ++i) b += red[i];
        atomicAdd(&ws[WS_TSUM], b);
    }
}

// ---------------------------------------------------------------------------
// Sum GB block-partials into gram+colsum (atomicAdd onto zeroed region).
// ---------------------------------------------------------------------------
__global__ __launch_bounds__(256) void reduce_partials(float* __restrict__ ws, int P, int slices) {
    const int nIdxBlocks = (PART_STRIDE + 255) / 256;      // 65
    const int idx   = (blockIdx.x % nIdxBlocks) * 256 + threadIdx.x;
    const int slice = blockIdx.x / nIdxBlocks;
    if (idx >= PART_STRIDE) return;
    const int per = P / slices;
    const float* part = ws + WS_PART;
    float s = 0.f;
    const int p0 = slice * per;
#pragma unroll 8
    for (int p = 0; p < per; ++p)
        s += part[(size_t)(p0 + p) * PART_STRIDE + idx];
    if (idx < D * D) atomicAdd(&ws[WS_GRAM + idx], s);
    else             atomicAdd(&ws[WS_COLSUM + (idx - D * D)], s);
}

// ---------------------------------------------------------------------------
// Finalize: cov/corr^2 tril mean + combine.
// ---------------------------------------------------------------------------
__global__ __launch_bounds__(256) void finalize_kernel(const float* __restrict__ ws,
                                                       float* __restrict__ out,
                                                       int N, int T) {
    const float* gram   = ws + WS_GRAM;
    const float* colsum = ws + WS_COLSUM;

    __shared__ float V[D];
    __shared__ float red[256];

    const int tid = threadIdx.x;
    const float invN   = 1.0f / (float)N;
    const float invNm1 = 1.0f / (float)(N - 1);

    if (tid < D) {
        float m = colsum[tid] * invN;
        V[tid] = (gram[tid * D + tid] - (float)N * m * m) * invNm1;
    }
    __syncthreads();

    float local = 0.f;
    for (int idx = tid; idx < D * D; idx += 256) {
        int i = idx >> 7, j = idx & 127;
        if (j < i) {
            float mi  = colsum[i] * invN;
            float mj  = colsum[j] * invN;
            float cov = (gram[idx] - (float)N * mi * mj) * invNm1;
            local += cov * cov / (V[i] * V[j]);
        }
    }
    red[tid] = local;
    __syncthreads();
    for (int s = 128; s > 0; s >>= 1) {
        if (tid < s) red[tid] += red[tid + s];
        __syncthreads();
    }
    if (tid == 0) {
        float corr_mean = red[0] / ((float)D * (float)(D - 1) * 0.5f);
        out[0] = ws[WS_TSUM] / (float)T + ALFA * corr_mean;
    }
}

// ---------------------------------------------------------------------------
// Fallback (ws too small for partials+table): atomic gram + fp32 triplet,
// block-specialized (R4-proven path).
// ---------------------------------------------------------------------------
__device__ __forceinline__ float d2diff(float4 p, float4 q, float4 r) {
    float ax = p.x - q.x, ay = p.y - q.y, az = p.z - q.z, aw = p.w - q.w;
    float bx = p.x - r.x, by = p.y - r.y, bz = p.z - r.z, bw = p.w - r.w;
    return (ax * ax + ay * ay + az * az + aw * aw)
         - (bx * bx + by * by + bz * bz + bw * bw);
}

__global__ __launch_bounds__(512, 4) void fused_fallback(const float* __restrict__ emb,
                                                         const int* __restrict__ trip,
                                                         int rowsPerBlock, int T,
                                                         float* __restrict__ ws) {
    __shared__ __align__(16) char lds[2][128 * 128];
    __shared__ float csred[D];
    const int tid = threadIdx.x;

    if (blockIdx.x < GB) {
        const int l = tid & 63, w = tid >> 6, r0 = blockIdx.x * rowsPerBlock;
        const int rT = w & 3, c0 = (w >> 2) * 2;
        f32x16 acc0 = {}, acc1 = {};
        float cs[4] = {0.f, 0.f, 0.f, 0.f};
        const int d0 = (tid & 31) * 4;

        auto stage = [&](int cc, int b) {
#pragma unroll
            for (int j = 0; j < 2; ++j) {
                const int k = j * 32 + (tid >> 5) * 2;
                const float* base = emb + (size_t)(r0 + cc * KC + k) * D + d0;
                float4 a = *(const float4*)base;
                float4 bv = *(const float4*)(base + D);
#pragma unroll
                for (int i = 0; i < 4; ++i) {
                    float av = ((const float*)&a)[i], bb = ((const float*)&bv)[i];
                    cs[i] += av + bb;
                    unsigned slotp = (unsigned)(k >> 3) ^ (unsigned)((tid & 31) & 7);
                    unsigned off = (unsigned)(d0 + i) * 128u + slotp * 16u + (unsigned)((k & 7) << 1);
                    *(unsigned*)(&lds[b][off]) = (unsigned)f2bf(av) | ((unsigned)f2bf(bb) << 16);
                }
            }
        };
        auto frag = [&](int t, int kb, int b) -> bf16x8 {
            const int d = t * 32 + (l & 31);
            const int k = kb + (l >> 5) * 8;
            unsigned slotp = (unsigned)(k >> 3) ^ ((unsigned)(d >> 2) & 7u);
            return *(const bf16x8*)(&lds[b][(unsigned)d * 128u + slotp * 16u]);
        };
        const int nChunks = rowsPerBlock / KC;
        stage(0, 0);
        for (int cc = 0; cc < nChunks; ++cc) {
            const int b = cc & 1;
            __syncthreads();
            if (cc + 1 < nChunks) stage(cc + 1, b ^ 1);
#pragma unroll
            for (int kb = 0; kb < KC; kb += 16) {
                bf16x8 fr = frag(rT, kb, b);
                bf16x8 f0 = frag(c0, kb, b);
                bf16x8 f1 = frag(c0 + 1, kb, b);
                acc0 = __builtin_amdgcn_mfma_f32_32x32x16_bf16(fr, f0, acc0, 0, 0, 0);
                acc1 = __builtin_amdgcn_mfma_f32_32x32x16_bf16(fr, f1, acc1, 0, 0, 0);
            }
        }
        __syncthreads();
        if (tid < D) csred[tid] = 0.f;
        __syncthreads();
#pragma unroll
        for (int i = 0; i < 4; ++i) atomicAdd(&csred[d0 + i], cs[i]);
        __syncthreads();
        if (tid < D) atomicAdd(&ws[WS_COLSUM + tid], csred[tid]);
        const int row_hi = (l >> 5) * 4, col = l & 31;
#pragma unroll
        for (int reg = 0; reg < 16; ++reg) {
            const int row32 = (reg & 3) + 8 * (reg >> 2) + row_hi;
            const int gr = (rT * 32 + row32) * D;
            atomicAdd(&ws[WS_GRAM + gr + c0 * 32 + col], acc0[reg]);
            atomicAdd(&ws[WS_GRAM + gr + (c0 + 1) * 32 + col], acc1[reg]);
        }
    } else {
        const int li = tid & 31, hwl = tid >> 5;
        const int hw = (blockIdx.x - GB) * 16 + hwl;
        const int NH = 1024 * 16;
        float wsum = 0.f;
        for (int t0 = hw; t0 < T; t0 += 4 * NH) {
            float4 P[4], Q[4], R[4];
#pragma unroll
            for (int k = 0; k < 4; ++k) {
                const int t = t0 + k * NH;
                if (t < T) {
                    const int i0 = trip[3 * t], i1 = trip[3 * t + 1], i2 = trip[3 * t + 2];
                    P[k] = ((const float4*)(emb + (size_t)i0 * D))[li];
                    Q[k] = ((const float4*)(emb + (size_t)i1 * D))[li];
                    R[k] = ((const float4*)(emb + (size_t)i2 * D))[li];
                }
            }
#pragma unroll
            for (int k = 0; k < 4; ++k) {
                const int t = t0 + k * NH;
                if (t < T) {
                    float s = d2diff(P[k], Q[k], R[k]);
#pragma unroll
                    for (int off = 16; off; off >>= 1) s += __shfl_xor(s, off, 64);
                    if (li == 0) wsum += fmaxf(s + MARGIN, 0.f);
                }
            }
        }
        if (li == 0) csred[hwl] = wsum;
        __syncthreads();
        if (tid == 0) {
            float b = 0.f;
#pragma unroll
            for (int i = 0; i < 16; ++i) b += csred[i];
            atomicAdd(&ws[WS_TSUM], b);
        }
    }
}

extern "C" void kernel_launch(void* const* d_in, const int* in_sizes, int n_in,
                              void* d_out, int out_size, void* d_ws, size_t ws_size,
                              hipStream_t stream) {
    const float* emb  = (const float*)d_in[0];
    const int*   trip = (const int*)d_in[1];
    float*       out  = (float*)d_out;
    float*       ws   = (float*)d_ws;

    const int N = in_sizes[0] / D;   // 262144
    const int T = in_sizes[1] / 3;   // 262144

    hipMemsetAsync(d_ws, 0, WS_ZERO * sizeof(float), stream);

    const size_t needB = (size_t)WS_TAB_F * 4 + (size_t)N * D * 2;   // partials + bf16 table

    if (ws_size >= needB) {
        unsigned short* tab = (unsigned short*)(ws + WS_TAB_F);
        gram_mfma_write<<<GB, 512, 0, stream>>>(emb, N / GB, ws, tab);
        triplet_bf16<<<1024, 256, 0, stream>>>(tab, trip, T, ws);
        reduce_partials<<<65 * 16, 256, 0, stream>>>(ws, GB, 16);
    } else {
        fused_fallback<<<GB + 1024, 512, 0, stream>>>(emb, trip, N / GB, T, ws);
    }

    finalize_kernel<<<1, 256, 0, stream>>>(ws, out, N, T);
}